// Round 1
// baseline (230.806 us; speedup 1.0000x reference)
//
#include <hip/hip_runtime.h>

// DigitCaps dynamic routing, B=512, N=4608, IN=16, OUT=32, CAPS=32.
// Identity: b-logits start at zero => softmax stays exactly uniform (1/32)
// across all 3 routing iterations (v is c-independent, so the agreement
// update is constant across c). Hence:
//   v[b,c,k] = squash_k((1/32) * sum_{n,j} x[b,n,j]*W[n,j,k])  for all c
// => one GEMM S[512,32] = X[512,73728] @ Wflat[73728,32], squash, broadcast.
//
// R4: fuse W-fragment formatting into the gemm (per-block LDS chunk,
// one barrier, bit-identical numerics) -> drops the wt_prep dispatch and
// the 14 MB global wt round-trip. The 8 row-group blocks sharing a k-chunk
// are 128 apart in flat block id (128 % 8 == 0) -> same XCD -> chunk is
// HBM-read once, L2-hit 7x. finalize rewritten 8x wider + coalesced
// (old: 2 waves/CU, 64-KiB-strided scalar loads, latency-bound).

#define NB 512
#define KTOT 73728          // N*IN
#define OUTC 32
#define NCAPS 32

// ---- MFMA path constants ----
#define KSPLIT 128
#define KCHUNK (KTOT / KSPLIT)        // 576
#define NSTEP (KCHUNK / 32)           // 18 k-steps of 32
#define SPA_BYTES ((size_t)KSPLIT * NB * OUTC * 4)       // 8,388,608
#define S_BYTES ((size_t)NB * OUTC * 4)                  // 65,536

typedef short bf16x8 __attribute__((ext_vector_type(8)));
typedef float f32x4 __attribute__((ext_vector_type(4)));

__device__ __forceinline__ unsigned int f2bf(float f) {
    union { float f; unsigned int u; } v; v.f = f;
    unsigned int u = v.u;
    return (u + 0x7fffu + ((u >> 16) & 1u)) >> 16;   // RNE to bf16 bits
}

// ---- streaming MFMA GEMM with fused W-chunk formatting ----
// B-fragment for mfma_f32_16x16x32_bf16: lane holds
// B[k = kstep + (lane>>4)*8 + j][n = lane&15], j=0..7 contiguous.
// LDS layout: [step 0..17][chalf 0..1][lane 0..63][j 0..7] bf16 = 36,864 B.
// A-frag: A[m=lane&15][k=(lane>>4)*8+j]; C/D: col=lane&15, row=(lane>>4)*4+reg.
template <bool PART>
__global__ __launch_bounds__(256) void gemm_mfma(
        const float* __restrict__ x, const float* __restrict__ w,
        float* __restrict__ S) {
    __shared__ __align__(16) unsigned short wl[NSTEP * 1024];
    const int t = threadIdx.x;
    const int lane = t & 63;
    const int wave = t >> 6;
    const int bx = blockIdx.x;               // k-split index
    const int by = blockIdx.y;               // row-group (8)
    const size_t kbase = (size_t)bx * KCHUNK;

    // --- format this block's W chunk into LDS B-fragments (once) ---
    // tuple tt = step*128 + h*64 + ll ; 2304 tuples / 256 threads = 9 each
    for (int tt = t; tt < NSTEP * 128; tt += 256) {
        int ll = tt & 63;
        int h = (tt >> 6) & 1;
        int step = tt >> 7;
        int k0 = step * 32 + ((ll >> 4) & 3) * 8;
        int c = h * 16 + (ll & 15);
        const float* wp0 = w + (kbase + (size_t)k0) * OUTC + c;
        unsigned int u[4];
#pragma unroll
        for (int j = 0; j < 4; ++j) {
            unsigned int lo = f2bf(wp0[(2 * j) * OUTC]);
            unsigned int hi = f2bf(wp0[(2 * j + 1) * OUTC]);
            u[j] = lo | (hi << 16);
        }
        *(uint4*)&wl[(size_t)tt * 8] = make_uint4(u[0], u[1], u[2], u[3]);
    }
    __syncthreads();

    const int row0 = by * 64 + wave * 16;
    const int m = lane & 15;
    const int q = lane >> 4;

    const float* xp = x + (size_t)(row0 + m) * KTOT + kbase + q * 8;
    const unsigned short* wp = wl + lane * 8;

    f32x4 acc0 = {0.f, 0.f, 0.f, 0.f};
    f32x4 acc1 = {0.f, 0.f, 0.f, 0.f};

#pragma unroll 6
    for (int s = 0; s < NSTEP; ++s) {
        float4 xa = *(const float4*)xp;
        float4 xb = *(const float4*)(xp + 4);
        xp += 32;
        bf16x8 b0 = *(const bf16x8*)(wp);
        bf16x8 b1 = *(const bf16x8*)(wp + 512);
        wp += 1024;
        bf16x8 a;
        a[0] = (short)f2bf(xa.x); a[1] = (short)f2bf(xa.y);
        a[2] = (short)f2bf(xa.z); a[3] = (short)f2bf(xa.w);
        a[4] = (short)f2bf(xb.x); a[5] = (short)f2bf(xb.y);
        a[6] = (short)f2bf(xb.z); a[7] = (short)f2bf(xb.w);
        acc0 = __builtin_amdgcn_mfma_f32_16x16x32_bf16(a, b0, acc0, 0, 0, 0);
        acc1 = __builtin_amdgcn_mfma_f32_16x16x32_bf16(a, b1, acc1, 0, 0, 0);
    }

    // epilogue: C/D col = m, row_local = q*4 + reg
#pragma unroll
    for (int r = 0; r < 4; ++r) {
        const int row = row0 + q * 4 + r;
        if (PART) {
            float* dst = S + ((size_t)bx * NB + row) * OUTC;
            dst[m] = acc0[r];
            dst[16 + m] = acc1[r];
        } else {
            atomicAdd(&S[(size_t)row * OUTC + m], acc0[r]);
            atomicAdd(&S[(size_t)row * OUTC + 16 + m], acc1[r]);
        }
    }
}

__global__ __launch_bounds__(256) void zero_s(float* __restrict__ S) {
    int i = blockIdx.x * 256 + threadIdx.x;
    if (i < NB * OUTC) S[i] = 0.0f;
}

// finalize v2: one block per batch row b; 256 threads = 8 split-groups x 32 k.
// Coalesced 128-B reads of the partials, 1-KB LDS cross-group reduce,
// squash via 5-step shfl, broadcast across the 32 identical capsules.
__global__ __launch_bounds__(256) void finalize2(const float* __restrict__ S,
                                                 float* __restrict__ out) {
    __shared__ float sm[8][32];
    const int b = blockIdx.x;
    const int t = threadIdx.x;
    const int k = t & 31;
    const int g = t >> 5;
    const float* sp = S + ((size_t)(g * 16) * NB + b) * OUTC + k;
    float a = 0.0f;
#pragma unroll 16
    for (int i = 0; i < 16; ++i)
        a += sp[(size_t)i * NB * OUTC];
    sm[g][k] = a;
    __syncthreads();
    float tot = 0.0f;
#pragma unroll
    for (int gg = 0; gg < 8; ++gg) tot += sm[gg][k];
    float s = tot * (1.0f / 32.0f);
    float sq = s * s;
    sq += __shfl_xor(sq, 16, 64);
    sq += __shfl_xor(sq, 8, 64);
    sq += __shfl_xor(sq, 4, 64);
    sq += __shfl_xor(sq, 2, 64);
    sq += __shfl_xor(sq, 1, 64);
    float scale = sq / ((1.0f + sq) * sqrtf(sq));   // squash
    float v = s * scale;
    float* orow = out + (size_t)b * (NCAPS * OUTC);
#pragma unroll
    for (int j = 0; j < 4; ++j)
        orow[(g * 4 + j) * OUTC + k] = v;           // broadcast across capsules
}

// finalize for the atomic tier: S is already the full [b][k] sum.
__global__ __launch_bounds__(64) void finalize_k(const float* __restrict__ S,
                                                 float* __restrict__ out) {
    const int b = blockIdx.x;
    const int t = threadIdx.x;
    const int k = t & 31;
    const int h = t >> 5;
    float s = S[(size_t)b * OUTC + k] * (1.0f / 32.0f);
    float sq = s * s;
    sq += __shfl_xor(sq, 16, 64);
    sq += __shfl_xor(sq, 8, 64);
    sq += __shfl_xor(sq, 4, 64);
    sq += __shfl_xor(sq, 2, 64);
    sq += __shfl_xor(sq, 1, 64);
    float scale = sq / ((1.0f + sq) * sqrtf(sq));   // squash
    float v = s * scale;
    float* orow = out + (size_t)b * (NCAPS * OUTC);
#pragma unroll
    for (int j = 0; j < 16; ++j)
        orow[(h + j * 2) * OUTC + k] = v;           // broadcast across capsules
}

// ---------- tier C fallback (proven R1/R2-style fp32 LDS kernel) ----------
#define FKSPLIT 64
#define FKCHUNK 1152
#define FKT 128
#define FNQ 32
#define FRPW 2
#define FKSTR 132

__global__ __launch_bounds__(256) void gemm_fb(
        const float* __restrict__ x, const float* __restrict__ w,
        float* __restrict__ S) {
    __shared__ float wlds[OUTC * FKSTR];
    const int t = threadIdx.x;
    const int lane = t & 63;
    const int l32 = lane & 31;
    const int half = lane >> 5;
    const int wave = t >> 6;
    const int row0 = blockIdx.x * 16 + wave * 4 + half * FRPW;
    const size_t kbase = (size_t)blockIdx.y * FKCHUNK;
    const int sc = t & 31;
    const int sh = t >> 5;

    float acc[FRPW][OUTC];
#pragma unroll
    for (int r = 0; r < FRPW; ++r)
#pragma unroll
        for (int c = 0; c < OUTC; ++c) acc[r][c] = 0.0f;

    const float4* xq[FRPW];
#pragma unroll
    for (int r = 0; r < FRPW; ++r)
        xq[r] = (const float4*)(x + (size_t)(row0 + r) * KTOT + kbase);

    for (int tile = 0; tile < FKCHUNK / FKT; ++tile) {
        float4 xv[FRPW];
#pragma unroll
        for (int r = 0; r < FRPW; ++r)
            xv[r] = xq[r][tile * FNQ + l32];
#pragma unroll
        for (int jj = 0; jj < 4; ++jj) {
            int kk = 4 * (jj * 8 + sh);
            const float* wg = w + (kbase + (size_t)tile * FKT + kk) * OUTC + sc;
            *(float4*)&wlds[sc * FKSTR + kk] =
                make_float4(wg[0], wg[OUTC], wg[2 * OUTC], wg[3 * OUTC]);
        }
        __syncthreads();
#pragma unroll
        for (int c = 0; c < OUTC; ++c) {
            float4 wv = *(const float4*)&wlds[c * FKSTR + 4 * l32];
#pragma unroll
            for (int r = 0; r < FRPW; ++r) {
                float a = acc[r][c];
                a = fmaf(xv[r].x, wv.x, a);
                a = fmaf(xv[r].y, wv.y, a);
                a = fmaf(xv[r].z, wv.z, a);
                a = fmaf(xv[r].w, wv.w, a);
                acc[r][c] = a;
            }
        }
        __syncthreads();
    }
#pragma unroll
    for (int r = 0; r < FRPW; ++r) {
        float myv = 0.0f;
#pragma unroll
        for (int c = 0; c < OUTC; ++c) {
            float v = acc[r][c];
            v += __shfl_xor(v, 16, 64);
            v += __shfl_xor(v, 8, 64);
            v += __shfl_xor(v, 4, 64);
            v += __shfl_xor(v, 2, 64);
            v += __shfl_xor(v, 1, 64);
            if (l32 == c) myv = v;
        }
        atomicAdd(&S[(size_t)(row0 + r) * OUTC + l32], myv);
    }
}
// --------------------------------------------------------------------------

extern "C" void kernel_launch(void* const* d_in, const int* in_sizes, int n_in,
                              void* d_out, int out_size, void* d_ws, size_t ws_size,
                              hipStream_t stream) {
    const float* x = (const float*)d_in[0];          // [512, 4608, 16] f32
    const float* w = (const float*)d_in[1];          // [4608, 16, 32] f32
    float* out = (float*)d_out;                      // [512, 32, 32] f32

    if (ws_size >= SPA_BYTES) {
        // Tier A: fused-format MFMA + split-K partials (no atomics, no zeroing)
        float* S = (float*)d_ws;
        hipLaunchKernelGGL((gemm_mfma<true>), dim3(KSPLIT, 8), dim3(256), 0,
                           stream, x, w, S);
        hipLaunchKernelGGL(finalize2, dim3(NB), dim3(256), 0, stream, S, out);
    } else if (ws_size >= S_BYTES) {
        // Tier B: fused-format MFMA + atomic accumulation
        float* S = (float*)d_ws;
        hipLaunchKernelGGL(zero_s, dim3((NB * OUTC + 255) / 256), dim3(256), 0,
                           stream, S);
        hipLaunchKernelGGL((gemm_mfma<false>), dim3(KSPLIT, 8), dim3(256), 0,
                           stream, x, w, S);
        hipLaunchKernelGGL(finalize_k, dim3(NB), dim3(64), 0, stream, S, out);
    } else {
        // Tier C: proven fp32 LDS fallback (needs only 64 KB)
        float* S = (float*)d_ws;
        hipLaunchKernelGGL(zero_s, dim3((NB * OUTC + 255) / 256), dim3(256), 0,
                           stream, S);
        hipLaunchKernelGGL(gemm_fb, dim3(32, FKSPLIT), dim3(256), 0, stream,
                           x, w, S);
        hipLaunchKernelGGL(finalize_k, dim3(NB), dim3(64), 0, stream, S, out);
    }
}

// Round 2
// 224.341 us; speedup vs baseline: 1.0288x; 1.0288x over previous
//
#include <hip/hip_runtime.h>

// DigitCaps dynamic routing, B=512, N=4608, IN=16, OUT=32, CAPS=32.
// Identity: b-logits start at zero => softmax stays exactly uniform (1/32)
// across all 3 routing iterations (v is c-independent, so the agreement
// update is constant across c). Hence:
//   v[b,c,k] = squash_k((1/32) * sum_{n,j} x[b,n,j]*W[n,j,k])  for all c
// => one GEMM S[512,32] = X[512,73728] @ Wflat[73728,32], squash, broadcast.
//
// R5: LDS-staged x-path. R4's hot loop loaded x in MFMA-fragment shape
// (16 rows x 64 B scattered per wave-instruction, rows 288 KiB apart) --
// every 64-B granule is a fresh DRAM page activation => ~55-65% HBM
// efficiency on the 151-MB x stream. Now: coalesced 256-B-per-row stage
// into LDS (4 rows x 256 B per instruction), bf16 conversion during stage,
// A-fragments via ds_read_b128. Next-tile global loads issued before the
// barrier (T14 split) so HBM latency hides under compute; 4 independent
// blocks/CU absorb barrier drains. Accumulation order and f2bf rounding
// unchanged -> bit-identical to R4.

#define NB 512
#define KTOT 73728          // N*IN
#define OUTC 32
#define NCAPS 32

// ---- MFMA path constants ----
#define KSPLIT 128
#define KCHUNK (KTOT / KSPLIT)        // 576
#define NTILE 9                       // tiles of 64 k per chunk
#define SPA_BYTES ((size_t)KSPLIT * NB * OUTC * 4)       // 8,388,608
#define S_BYTES ((size_t)NB * OUTC * 4)                  // 65,536

typedef short bf16x8 __attribute__((ext_vector_type(8)));
typedef float f32x4 __attribute__((ext_vector_type(4)));

__device__ __forceinline__ unsigned int f2bf(float f) {
    union { float f; unsigned int u; } v; v.f = f;
    unsigned int u = v.u;
    return (u + 0x7fffu + ((u >> 16) & 1u)) >> 16;   // RNE to bf16 bits
}

// ---- LDS-staged MFMA GEMM ----
// Per block: 64 rows (by) x 576 k (bx), 9 tiles of 64 k.
// W-LDS  [sl 0..1][h 0..1][lane 0..63][j 0..7] bf16 = 4 KB (B-fragments).
// X-LDS  [w 0..3][sl 0..1][m 0..15][q 0..3][j 0..7] bf16 = 8 KB (A-fragments).
// A-frag: lane(m,q) holds A[m][sl*32 + q*8 + j]; C/D: col=lane&15,
// row=(lane>>4)*4+reg (verified layouts).
template <bool PART>
__global__ __launch_bounds__(256) void gemm_mfma(
        const float* __restrict__ x, const float* __restrict__ w,
        float* __restrict__ S) {
    __shared__ __align__(16) unsigned short wl[2048];
    __shared__ __align__(16) unsigned short xl[4096];
    const int t = threadIdx.x;
    const int lane = t & 63;
    const int wave = t >> 6;
    const int bx = blockIdx.x;               // k-split index
    const int by = blockIdx.y;               // row-group (8)
    const int brow = by * 64;
    const size_t kbase = (size_t)bx * KCHUNK;

    const int m = lane & 15;
    const int q = lane >> 4;

    // X-stage mapping: thread (sr_, sm_) reads float4 slot sm_ of row
    // brow + sr_ + 16*ld  => per wave-instruction: 4 rows x 256 B contiguous.
    const int sm_ = t & 15;
    const int sr_ = t >> 4;
    const int xsl = sm_ >> 3;                // k-local = sm_*4
    const int xq  = (sm_ >> 1) & 3;
    const int xj0 = (sm_ & 1) * 4;
    // W-stage mapping: one B-fragment tuple per thread (t = slw*128+h*64+ll).
    const int ll  = t & 63;
    const int h   = (t >> 6) & 1;
    const int slw = t >> 7;
    const int wk0 = slw * 32 + ((ll >> 4) & 3) * 8;
    const int wc  = h * 16 + (ll & 15);

    f32x4 acc0 = {0.f, 0.f, 0.f, 0.f};
    f32x4 acc1 = {0.f, 0.f, 0.f, 0.f};

    float  wr[8];
    float4 xr[4];

    // prefetch tile 0
    {
        const float* wp0 = w + (kbase + (size_t)wk0) * OUTC + wc;
#pragma unroll
        for (int j = 0; j < 8; ++j) wr[j] = wp0[(size_t)j * OUTC];
        const float* xb = x + kbase + sm_ * 4;
#pragma unroll
        for (int ld = 0; ld < 4; ++ld)
            xr[ld] = *(const float4*)(xb + (size_t)(brow + sr_ + ld * 16) * KTOT);
    }

    for (int tile = 0; tile < NTILE; ++tile) {
        // ---- write staged tile (regs -> LDS, bf16 conversion here) ----
        {
            unsigned int u0 = f2bf(wr[0]) | (f2bf(wr[1]) << 16);
            unsigned int u1 = f2bf(wr[2]) | (f2bf(wr[3]) << 16);
            unsigned int u2 = f2bf(wr[4]) | (f2bf(wr[5]) << 16);
            unsigned int u3 = f2bf(wr[6]) | (f2bf(wr[7]) << 16);
            *(uint4*)&wl[t * 8] = make_uint4(u0, u1, u2, u3);
#pragma unroll
            for (int ld = 0; ld < 4; ++ld) {
                unsigned int a0 = f2bf(xr[ld].x) | (f2bf(xr[ld].y) << 16);
                unsigned int a1 = f2bf(xr[ld].z) | (f2bf(xr[ld].w) << 16);
                *(uint2*)&xl[((ld * 2 + xsl) * 16 + sr_) * 32 + xq * 8 + xj0] =
                    make_uint2(a0, a1);
            }
        }
        // ---- issue next tile's global loads (land during compute) ----
        if (tile + 1 < NTILE) {
            const size_t kt = kbase + (size_t)(tile + 1) * 64;
            const float* wp0 = w + (kt + (size_t)wk0) * OUTC + wc;
#pragma unroll
            for (int j = 0; j < 8; ++j) wr[j] = wp0[(size_t)j * OUTC];
            const float* xb = x + kt + sm_ * 4;
#pragma unroll
            for (int ld = 0; ld < 4; ++ld)
                xr[ld] = *(const float4*)(xb + (size_t)(brow + sr_ + ld * 16) * KTOT);
        }
        __syncthreads();
        // ---- compute: 2 k-steps of 32, fragments from LDS ----
#pragma unroll
        for (int sl = 0; sl < 2; ++sl) {
            bf16x8 a  = *(const bf16x8*)&xl[((wave * 2 + sl) * 16 + m) * 32 + q * 8];
            bf16x8 b0 = *(const bf16x8*)&wl[sl * 1024 + lane * 8];
            bf16x8 b1 = *(const bf16x8*)&wl[sl * 1024 + 512 + lane * 8];
            acc0 = __builtin_amdgcn_mfma_f32_16x16x32_bf16(a, b0, acc0, 0, 0, 0);
            acc1 = __builtin_amdgcn_mfma_f32_16x16x32_bf16(a, b1, acc1, 0, 0, 0);
        }
        __syncthreads();
    }

    // epilogue: C/D col = m, row_local = q*4 + reg
    const int row0 = brow + wave * 16;
#pragma unroll
    for (int r = 0; r < 4; ++r) {
        const int row = row0 + q * 4 + r;
        if (PART) {
            float* dst = S + ((size_t)bx * NB + row) * OUTC;
            dst[m] = acc0[r];
            dst[16 + m] = acc1[r];
        } else {
            atomicAdd(&S[(size_t)row * OUTC + m], acc0[r]);
            atomicAdd(&S[(size_t)row * OUTC + 16 + m], acc1[r]);
        }
    }
}

__global__ __launch_bounds__(256) void zero_s(float* __restrict__ S) {
    int i = blockIdx.x * 256 + threadIdx.x;
    if (i < NB * OUTC) S[i] = 0.0f;
}

// finalize v2: one block per batch row b; 256 threads = 8 split-groups x 32 k.
// Coalesced 128-B reads of the partials, 1-KB LDS cross-group reduce,
// squash via 5-step shfl, broadcast across the 32 identical capsules.
__global__ __launch_bounds__(256) void finalize2(const float* __restrict__ S,
                                                 float* __restrict__ out) {
    __shared__ float sm[8][32];
    const int b = blockIdx.x;
    const int t = threadIdx.x;
    const int k = t & 31;
    const int g = t >> 5;
    const float* sp = S + ((size_t)(g * 16) * NB + b) * OUTC + k;
    float a = 0.0f;
#pragma unroll 16
    for (int i = 0; i < 16; ++i)
        a += sp[(size_t)i * NB * OUTC];
    sm[g][k] = a;
    __syncthreads();
    float tot = 0.0f;
#pragma unroll
    for (int gg = 0; gg < 8; ++gg) tot += sm[gg][k];
    float s = tot * (1.0f / 32.0f);
    float sq = s * s;
    sq += __shfl_xor(sq, 16, 64);
    sq += __shfl_xor(sq, 8, 64);
    sq += __shfl_xor(sq, 4, 64);
    sq += __shfl_xor(sq, 2, 64);
    sq += __shfl_xor(sq, 1, 64);
    float scale = sq / ((1.0f + sq) * sqrtf(sq));   // squash
    float v = s * scale;
    float* orow = out + (size_t)b * (NCAPS * OUTC);
#pragma unroll
    for (int j = 0; j < 4; ++j)
        orow[(g * 4 + j) * OUTC + k] = v;           // broadcast across capsules
}

// finalize for the atomic tier: S is already the full [b][k] sum.
__global__ __launch_bounds__(64) void finalize_k(const float* __restrict__ S,
                                                 float* __restrict__ out) {
    const int b = blockIdx.x;
    const int t = threadIdx.x;
    const int k = t & 31;
    const int h = t >> 5;
    float s = S[(size_t)b * OUTC + k] * (1.0f / 32.0f);
    float sq = s * s;
    sq += __shfl_xor(sq, 16, 64);
    sq += __shfl_xor(sq, 8, 64);
    sq += __shfl_xor(sq, 4, 64);
    sq += __shfl_xor(sq, 2, 64);
    sq += __shfl_xor(sq, 1, 64);
    float scale = sq / ((1.0f + sq) * sqrtf(sq));   // squash
    float v = s * scale;
    float* orow = out + (size_t)b * (NCAPS * OUTC);
#pragma unroll
    for (int j = 0; j < 16; ++j)
        orow[(h + j * 2) * OUTC + k] = v;           // broadcast across capsules
}

// ---------- tier C fallback (proven R1/R2-style fp32 LDS kernel) ----------
#define FKSPLIT 64
#define FKCHUNK 1152
#define FKT 128
#define FNQ 32
#define FRPW 2
#define FKSTR 132

__global__ __launch_bounds__(256) void gemm_fb(
        const float* __restrict__ x, const float* __restrict__ w,
        float* __restrict__ S) {
    __shared__ float wlds[OUTC * FKSTR];
    const int t = threadIdx.x;
    const int lane = t & 63;
    const int l32 = lane & 31;
    const int half = lane >> 5;
    const int wave = t >> 6;
    const int row0 = blockIdx.x * 16 + wave * 4 + half * FRPW;
    const size_t kbase = (size_t)blockIdx.y * FKCHUNK;
    const int sc = t & 31;
    const int sh = t >> 5;

    float acc[FRPW][OUTC];
#pragma unroll
    for (int r = 0; r < FRPW; ++r)
#pragma unroll
        for (int c = 0; c < OUTC; ++c) acc[r][c] = 0.0f;

    const float4* xq[FRPW];
#pragma unroll
    for (int r = 0; r < FRPW; ++r)
        xq[r] = (const float4*)(x + (size_t)(row0 + r) * KTOT + kbase);

    for (int tile = 0; tile < FKCHUNK / FKT; ++tile) {
        float4 xv[FRPW];
#pragma unroll
        for (int r = 0; r < FRPW; ++r)
            xv[r] = xq[r][tile * FNQ + l32];
#pragma unroll
        for (int jj = 0; jj < 4; ++jj) {
            int kk = 4 * (jj * 8 + sh);
            const float* wg = w + (kbase + (size_t)tile * FKT + kk) * OUTC + sc;
            *(float4*)&wlds[sc * FKSTR + kk] =
                make_float4(wg[0], wg[OUTC], wg[2 * OUTC], wg[3 * OUTC]);
        }
        __syncthreads();
#pragma unroll
        for (int c = 0; c < OUTC; ++c) {
            float4 wv = *(const float4*)&wlds[c * FKSTR + 4 * l32];
#pragma unroll
            for (int r = 0; r < FRPW; ++r) {
                float a = acc[r][c];
                a = fmaf(xv[r].x, wv.x, a);
                a = fmaf(xv[r].y, wv.y, a);
                a = fmaf(xv[r].z, wv.z, a);
                a = fmaf(xv[r].w, wv.w, a);
                acc[r][c] = a;
            }
        }
        __syncthreads();
    }
#pragma unroll
    for (int r = 0; r < FRPW; ++r) {
        float myv = 0.0f;
#pragma unroll
        for (int c = 0; c < OUTC; ++c) {
            float v = acc[r][c];
            v += __shfl_xor(v, 16, 64);
            v += __shfl_xor(v, 8, 64);
            v += __shfl_xor(v, 4, 64);
            v += __shfl_xor(v, 2, 64);
            v += __shfl_xor(v, 1, 64);
            if (l32 == c) myv = v;
        }
        atomicAdd(&S[(size_t)(row0 + r) * OUTC + l32], myv);
    }
}
// --------------------------------------------------------------------------

extern "C" void kernel_launch(void* const* d_in, const int* in_sizes, int n_in,
                              void* d_out, int out_size, void* d_ws, size_t ws_size,
                              hipStream_t stream) {
    const float* x = (const float*)d_in[0];          // [512, 4608, 16] f32
    const float* w = (const float*)d_in[1];          // [4608, 16, 32] f32
    float* out = (float*)d_out;                      // [512, 32, 32] f32

    if (ws_size >= SPA_BYTES) {
        // Tier A: LDS-staged MFMA + split-K partials (no atomics, no zeroing)
        float* S = (float*)d_ws;
        hipLaunchKernelGGL((gemm_mfma<true>), dim3(KSPLIT, 8), dim3(256), 0,
                           stream, x, w, S);
        hipLaunchKernelGGL(finalize2, dim3(NB), dim3(256), 0, stream, S, out);
    } else if (ws_size >= S_BYTES) {
        // Tier B: LDS-staged MFMA + atomic accumulation
        float* S = (float*)d_ws;
        hipLaunchKernelGGL(zero_s, dim3((NB * OUTC + 255) / 256), dim3(256), 0,
                           stream, S);
        hipLaunchKernelGGL((gemm_mfma<false>), dim3(KSPLIT, 8), dim3(256), 0,
                           stream, x, w, S);
        hipLaunchKernelGGL(finalize_k, dim3(NB), dim3(64), 0, stream, S, out);
    } else {
        // Tier C: proven fp32 LDS fallback (needs only 64 KB)
        float* S = (float*)d_ws;
        hipLaunchKernelGGL(zero_s, dim3((NB * OUTC + 255) / 256), dim3(256), 0,
                           stream, S);
        hipLaunchKernelGGL(gemm_fb, dim3(32, FKSPLIT), dim3(256), 0, stream,
                           x, w, S);
        hipLaunchKernelGGL(finalize_k, dim3(NB), dim3(64), 0, stream, S, out);
    }
}